// Round 8
// baseline (325.007 us; speedup 1.0000x reference)
//
#include <hip/hip_runtime.h>

#define IH 4096
#define IW 4096
#define KH 16
#define KW 16
#define OH 4081
#define OW 4081

#define TBR 64      // output rows per block
#define TBC 128     // output cols per tile
#define NT  4       // tiles marched in x per block
#define LROWS 79    // TBR + 15
#define LSTR 192    // bf16 per x-tile LDS row (24 chunks of 8; xor-swizzle closed)
#define NLOAD (LROWS * 36)   // 2844 float4 loads per tile

typedef short bf16x8 __attribute__((ext_vector_type(8)));
typedef float f32x4  __attribute__((ext_vector_type(4)));

static __device__ __forceinline__ unsigned int f2bf(float f) {
    unsigned int u = __float_as_uint(f);
    return (u + 0x7FFFu + ((u >> 16) & 1u)) >> 16;   // RTNE
}

// ---- pre-kernel: B[k=(u,v')][n] = w[u][v'-n] (0 outside band), bf16 ----
// ws layout: idx = u*512 + n*32 + v'   (16 KB)
__global__ void build_B(const float* __restrict__ wgt, unsigned short* __restrict__ Btab) {
    int idx = blockIdx.x * 256 + threadIdx.x;      // 0..8191
    if (idx >= 16 * 16 * 32) return;
    int vp = idx & 31;
    int n  = (idx >> 5) & 15;
    int u  = idx >> 9;
    int t  = vp - n;
    float val = (t >= 0 && t < KW) ? wgt[u * KW + t] : 0.0f;
    Btab[idx] = (unsigned short)f2bf(val);
}

// R8: intra-block stage/compute overlap (convoy-breaking).
// R3->R7 showed time is occupancy-insensitive (2 vs 4 blocks/CU, both ~49us)
// with no pipe >41% busy: phase-locked convoys (all blocks stage together,
// MFMA together). Fix: each block marches NT=4 tiles in x with double-
// buffered LDS; tile j+1's global loads are issued BEFORE tile j's MFMA
// loop (latency hides under ~6k cyc of compute), cvt+ds_write after, one
// barrier per tile. Depth-1 reg prefetch of B and A in the u-loop removes
// the serial per-u load-wait chain (VGPR 28 was "nothing in flight").
static __device__ __forceinline__ void load_tile(const float* __restrict__ x,
                                                 int gy0, int gx0, int tid,
                                                 float4 (&g)[6]) {
#pragma unroll
    for (int s = 0; s < 6; ++s) {
        int idx = tid + s * 512;
        float4 q = make_float4(0.f, 0.f, 0.f, 0.f);
        if (s < 5 || tid < (NLOAD - 5 * 512)) {
            int row = idx / 36;
            int c   = idx - row * 36;      // float4 index, col = 4c
            int gy  = gy0 + row;
            int gx  = gx0 + 4 * c;
            if (gy < IH) {
                if (gx + 4 <= IW) {
                    q = *reinterpret_cast<const float4*>(x + (size_t)gy * IW + gx);
                } else {
                    float e0 = (gx + 0 < IW) ? x[(size_t)gy * IW + gx + 0] : 0.f;
                    float e1 = (gx + 1 < IW) ? x[(size_t)gy * IW + gx + 1] : 0.f;
                    float e2 = (gx + 2 < IW) ? x[(size_t)gy * IW + gx + 2] : 0.f;
                    float e3 = (gx + 3 < IW) ? x[(size_t)gy * IW + gx + 3] : 0.f;
                    q = make_float4(e0, e1, e2, e3);
                }
            }
        }
        g[s] = q;
    }
}

static __device__ __forceinline__ void cvt_write(const float4 (&g)[6],
                                                 unsigned short* buf, int tid) {
#pragma unroll
    for (int s = 0; s < 6; ++s) {
        int idx = tid + s * 512;
        if (s < 5 || tid < (NLOAD - 5 * 512)) {
            int row = idx / 36;
            int c   = idx - row * 36;
            uint2 packed;
            packed.x = f2bf(g[s].x) | (f2bf(g[s].y) << 16);
            packed.y = f2bf(g[s].z) | (f2bf(g[s].w) << 16);
            int chunk = c >> 1;
            int half  = c & 1;
            int phys  = chunk ^ (row & 7);
            *reinterpret_cast<uint2*>(&buf[row * LSTR + phys * 8 + half * 4]) = packed;
        }
    }
}

__global__ __launch_bounds__(512, 4)
void conv_mfma(const float* __restrict__ x,
               const unsigned short* __restrict__ Btab,
               const float* __restrict__ bias,
               float* __restrict__ out) {
    __shared__ unsigned short tile[2][LROWS * LSTR];   // 2 x 29.6 KB

    const int tid  = threadIdx.x;
    const int lane = tid & 63;
    const int wv   = tid >> 6;        // 0..7
    const int n    = lane & 15;       // A row m / B col n / C col
    const int q4   = lane >> 4;       // quad 0..3
    const int gy0  = blockIdx.y * TBR;
    const int gx_base = blockIdx.x * (NT * TBC);

    const int rb  = wv >> 1;          // 0..3
    const int cg  = wv & 1;           // 0..1
    const int li0 = rb * 16;
    const int cbase = cg * 8 + q4;    // + 2t, then ^ (row&7)
    const unsigned short* bbase = Btab + n * 32 + q4 * 8;   // 16B-aligned
    const float bv = bias[0];

    // ---- prologue: stage tile 0 ----
    {
        float4 g0[6];
        load_tile(x, gy0, gx_base, tid, g0);
        cvt_write(g0, &tile[0][0], tid);
    }
    __syncthreads();

#pragma unroll 1
    for (int j = 0; j < NT; ++j) {
        const int gx0 = gx_base + j * TBC;
        const bool pre = (j + 1 < NT);

        // issue next tile's global loads; values consumed only after MFMA
        float4 gn[6];
        if (pre) load_tile(x, gy0, gx0 + TBC, tid, gn);

        const unsigned short* buf = &tile[j & 1][0];

        f32x4 acc0 = {0.f, 0.f, 0.f, 0.f};
        f32x4 acc1 = {0.f, 0.f, 0.f, 0.f};
        f32x4 acc2 = {0.f, 0.f, 0.f, 0.f};
        f32x4 acc3 = {0.f, 0.f, 0.f, 0.f};

        // depth-1 software pipeline over u
        bf16x8 b_c = *reinterpret_cast<const bf16x8*>(bbase);
        {
        }
        int row0 = li0 + n;
        int swz0 = row0 & 7;
        const unsigned short* rb0 = buf + row0 * LSTR;
        bf16x8 a_c0 = *reinterpret_cast<const bf16x8*>(rb0 + ((cbase + 0) ^ swz0) * 8);
        bf16x8 a_c1 = *reinterpret_cast<const bf16x8*>(rb0 + ((cbase + 2) ^ swz0) * 8);
        bf16x8 a_c2 = *reinterpret_cast<const bf16x8*>(rb0 + ((cbase + 4) ^ swz0) * 8);
        bf16x8 a_c3 = *reinterpret_cast<const bf16x8*>(rb0 + ((cbase + 6) ^ swz0) * 8);

#pragma unroll
        for (int u = 0; u < KH; ++u) {
            bf16x8 b_n, a_n0, a_n1, a_n2, a_n3;
            if (u < KH - 1) {
                b_n = *reinterpret_cast<const bf16x8*>(bbase + (u + 1) * 512);
                int row = li0 + n + u + 1;
                int swz = row & 7;
                const unsigned short* rbn = buf + row * LSTR;
                a_n0 = *reinterpret_cast<const bf16x8*>(rbn + ((cbase + 0) ^ swz) * 8);
                a_n1 = *reinterpret_cast<const bf16x8*>(rbn + ((cbase + 2) ^ swz) * 8);
                a_n2 = *reinterpret_cast<const bf16x8*>(rbn + ((cbase + 4) ^ swz) * 8);
                a_n3 = *reinterpret_cast<const bf16x8*>(rbn + ((cbase + 6) ^ swz) * 8);
            }
            acc0 = __builtin_amdgcn_mfma_f32_16x16x32_bf16(a_c0, b_c, acc0, 0, 0, 0);
            acc1 = __builtin_amdgcn_mfma_f32_16x16x32_bf16(a_c1, b_c, acc1, 0, 0, 0);
            acc2 = __builtin_amdgcn_mfma_f32_16x16x32_bf16(a_c2, b_c, acc2, 0, 0, 0);
            acc3 = __builtin_amdgcn_mfma_f32_16x16x32_bf16(a_c3, b_c, acc3, 0, 0, 0);
            if (u < KH - 1) {
                b_c = b_n;
                a_c0 = a_n0; a_c1 = a_n1; a_c2 = a_n2; a_c3 = a_n3;
            }
        }

        // ---- epilogue: C/D layout col=lane&15, row=quad*4+reg ----
        const int orow0 = gy0 + li0 + q4 * 4;
        const int ocol0 = gx0 + cg * 64 + n;
#pragma unroll
        for (int t = 0; t < 4; ++t) {
            const f32x4 acc = (t == 0) ? acc0 : (t == 1) ? acc1 : (t == 2) ? acc2 : acc3;
            int col = ocol0 + t * 16;
            if (col < OW) {
#pragma unroll
                for (int r = 0; r < 4; ++r) {
                    int rr = orow0 + r;
                    if (rr < OH) out[(size_t)rr * OW + col] = acc[r] + bv;
                }
            }
        }

        // ---- write next tile into the other buffer; one barrier per tile ----
        if (pre) {
            cvt_write(gn, &tile[(j + 1) & 1][0], tid);
            __syncthreads();
        }
    }
}

extern "C" void kernel_launch(void* const* d_in, const int* in_sizes, int n_in,
                              void* d_out, int out_size, void* d_ws, size_t ws_size,
                              hipStream_t stream) {
    const float* x  = (const float*)d_in[0];
    const float* w  = (const float*)d_in[1];
    const float* b  = (const float*)d_in[2];
    float* out = (float*)d_out;
    unsigned short* Btab = (unsigned short*)d_ws;

    build_B<<<32, 256, 0, stream>>>(w, Btab);

    // 32 x-tiles of 128 cols -> 8 blocks of NT=4; 64 y-blocks of 64 rows
    dim3 grid(8, 64);
    conv_mfma<<<grid, dim3(512), 0, stream>>>(x, Btab, b, out);
}

// Round 19
// 164.534 us; speedup vs baseline: 1.9753x; 1.9753x over previous
//
#include <hip/hip_runtime.h>

#define IH 4096
#define IW 4096
#define KH 16
#define KW 16
#define OH 4081
#define OW 4081

#define TBR 64      // output rows per block
#define TBC 128     // output cols per block
#define LROWS 79    // TBR + 15
#define LSTR 192    // bf16 per x-tile LDS row (24 chunks of 8; xor-swizzle closed)

typedef short bf16x8 __attribute__((ext_vector_type(8)));
typedef float f32x4  __attribute__((ext_vector_type(4)));

static __device__ __forceinline__ unsigned int f2bf(float f) {
    unsigned int u = __float_as_uint(f);
    return (u + 0x7FFFu + ((u >> 16) & 1u)) >> 16;   // RTNE
}

// ---- pre-kernel: B[k=(u,v')][n] = w[u][v'-n] (0 outside band), bf16 ----
// ws layout: idx = u*512 + n*32 + v'   (16 KB)
__global__ void build_B(const float* __restrict__ wgt, unsigned short* __restrict__ Btab) {
    int idx = blockIdx.x * 256 + threadIdx.x;      // 0..8191
    if (idx >= 16 * 16 * 32) return;
    int vp = idx & 31;
    int n  = (idx >> 5) & 15;
    int u  = idx >> 9;
    int t  = vp - n;
    float val = (t >= 0 && t < KW) ? wgt[u * KW + t] : 0.0f;
    Btab[idx] = (unsigned short)f2bf(val);
}

// R9: exact revert to the verified R7 kernel (50.2 us/dispatch) with ONE
// change: non-temporal epilogue stores. Evidence: across R3/R7/R8,
// dur == hbm_bytes / 2.39 TB/s within 2% -> purely memory-system-bound;
// occupancy and in-loop stalls are passengers. Theory: the 70 MB write
// stream churns the LLC and evicts x (64 MB, would otherwise stay
// resident across iterations -> the 46 MB re-FETCH). Output has zero
// reuse: nt stores bypass the cache, freeing the LLC for x.
__global__ __launch_bounds__(512, 8)
void conv_mfma(const float* __restrict__ x,
               const unsigned short* __restrict__ Btab,
               const float* __restrict__ bias,
               float* __restrict__ out) {
    __shared__ unsigned short tile[LROWS * LSTR];   // 29.6 KB x-tile (bf16)

    const int tid  = threadIdx.x;
    const int lane = tid & 63;
    const int wv   = tid >> 6;        // 0..7
    const int n    = lane & 15;       // A row m / B col n / C col
    const int q4   = lane >> 4;       // quad 0..3
    const int gy0  = blockIdx.y * TBR;
    const int gx0  = blockIdx.x * TBC;

    // ---- stage x tile: 79 rows x 144 cols fp32 -> bf16 LDS, chunk-xor swizzle ----
    for (int idx = tid; idx < LROWS * 36; idx += 512) {
        int row = idx / 36;
        int c   = idx - row * 36;      // float4 index, col = 4c
        int gy  = gy0 + row;
        int gx  = gx0 + 4 * c;
        float4 q = make_float4(0.f, 0.f, 0.f, 0.f);
        if (gy < IH) {
            if (gx + 4 <= IW) {
                q = *reinterpret_cast<const float4*>(x + (size_t)gy * IW + gx);
            } else {
                float e0 = (gx + 0 < IW) ? x[(size_t)gy * IW + gx + 0] : 0.f;
                float e1 = (gx + 1 < IW) ? x[(size_t)gy * IW + gx + 1] : 0.f;
                float e2 = (gx + 2 < IW) ? x[(size_t)gy * IW + gx + 2] : 0.f;
                float e3 = (gx + 3 < IW) ? x[(size_t)gy * IW + gx + 3] : 0.f;
                q = make_float4(e0, e1, e2, e3);
            }
        }
        uint2 packed;
        packed.x = f2bf(q.x) | (f2bf(q.y) << 16);
        packed.y = f2bf(q.z) | (f2bf(q.w) << 16);
        int chunk = c >> 1;
        int half  = c & 1;
        int phys  = chunk ^ (row & 7);
        *reinterpret_cast<uint2*>(&tile[row * LSTR + phys * 8 + half * 4]) = packed;
    }
    __syncthreads();

    // ---- MFMA main: wave = 1 row-block x 4 col-blocks of 16x16 C-tiles ----
    const int rb  = wv >> 1;          // 0..3
    const int cg  = wv & 1;           // 0..1
    const int li0 = rb * 16;

    f32x4 acc0 = {0.f, 0.f, 0.f, 0.f};
    f32x4 acc1 = {0.f, 0.f, 0.f, 0.f};
    f32x4 acc2 = {0.f, 0.f, 0.f, 0.f};
    f32x4 acc3 = {0.f, 0.f, 0.f, 0.f};

    const int cbase = cg * 8 + q4;    // + 2t, then ^ (row&7)
    const unsigned short* bbase = Btab + n * 32 + q4 * 8;   // 16B-aligned

#pragma unroll
    for (int u = 0; u < KH; ++u) {
        bf16x8 bf = *reinterpret_cast<const bf16x8*>(bbase + u * 512);
        int row = li0 + n + u;
        int swz = row & 7;
        const unsigned short* rbase = &tile[row * LSTR];
        bf16x8 a0 = *reinterpret_cast<const bf16x8*>(rbase + ((cbase + 0) ^ swz) * 8);
        bf16x8 a1 = *reinterpret_cast<const bf16x8*>(rbase + ((cbase + 2) ^ swz) * 8);
        bf16x8 a2 = *reinterpret_cast<const bf16x8*>(rbase + ((cbase + 4) ^ swz) * 8);
        bf16x8 a3 = *reinterpret_cast<const bf16x8*>(rbase + ((cbase + 6) ^ swz) * 8);
        acc0 = __builtin_amdgcn_mfma_f32_16x16x32_bf16(a0, bf, acc0, 0, 0, 0);
        acc1 = __builtin_amdgcn_mfma_f32_16x16x32_bf16(a1, bf, acc1, 0, 0, 0);
        acc2 = __builtin_amdgcn_mfma_f32_16x16x32_bf16(a2, bf, acc2, 0, 0, 0);
        acc3 = __builtin_amdgcn_mfma_f32_16x16x32_bf16(a3, bf, acc3, 0, 0, 0);
    }

    // ---- epilogue: C/D layout col=lane&15, row=quad*4+reg; nt stores ----
    const float bv = bias[0];
    const int orow0 = gy0 + li0 + q4 * 4;
    const int ocol0 = gx0 + cg * 64 + n;

#pragma unroll
    for (int t = 0; t < 4; ++t) {
        const f32x4 acc = (t == 0) ? acc0 : (t == 1) ? acc1 : (t == 2) ? acc2 : acc3;
        int col = ocol0 + t * 16;
        if (col < OW) {
#pragma unroll
            for (int r = 0; r < 4; ++r) {
                int rr = orow0 + r;
                if (rr < OH)
                    __builtin_nontemporal_store(acc[r] + bv, &out[(size_t)rr * OW + col]);
            }
        }
    }
}

extern "C" void kernel_launch(void* const* d_in, const int* in_sizes, int n_in,
                              void* d_out, int out_size, void* d_ws, size_t ws_size,
                              hipStream_t stream) {
    const float* x  = (const float*)d_in[0];
    const float* w  = (const float*)d_in[1];
    const float* b  = (const float*)d_in[2];
    float* out = (float*)d_out;
    unsigned short* Btab = (unsigned short*)d_ws;

    build_B<<<32, 256, 0, stream>>>(w, Btab);

    dim3 grid((OW + TBC - 1) / TBC, (OH + TBR - 1) / TBR);  // 32 x 64
    conv_mfma<<<grid, dim3(512), 0, stream>>>(x, Btab, b, out);
}